// Round 8
// baseline (149.083 us; speedup 1.0000x reference)
//
#include <hip/hip_runtime.h>
#include <hip/hip_bf16.h>
#include <cmath>

// ---------- types ----------
typedef __attribute__((ext_vector_type(8))) short bf16x8;    // 8 bf16 (4 VGPRs) MFMA A/B frag
typedef __attribute__((ext_vector_type(4))) float f32x4;     // 16x16 C/D frag
typedef __attribute__((ext_vector_type(16))) float f32x16;   // 32x32 C/D frag

__device__ __forceinline__ unsigned short f2bf(float f) {
    union { float f; unsigned int i; } c; c.f = f;
    unsigned int i = c.i;
    unsigned int r = i + 0x7FFF + ((i >> 16) & 1);   // RTNE
    return (unsigned short)(r >> 16);
}

__device__ __forceinline__ float fast_exp2(float x) {   // D = 2^x (v_exp_f32)
    float r;
    asm("v_exp_f32 %0, %1" : "=v"(r) : "v"(x));
    return r;
}

// async global->LDS, 16B/lane. LDS dest: wave-uniform base (+lane*16 implicit); global src per-lane.
__device__ __forceinline__ void gload_lds16(const unsigned short* g, unsigned short* l) {
    __builtin_amdgcn_global_load_lds((const __attribute__((address_space(1))) unsigned int*)g,
                                     (__attribute__((address_space(3))) unsigned int*)l, 16, 0, 0);
}

__device__ __forceinline__ float bperm_f(int srclane, float v) {
    return __int_as_float(__builtin_amdgcn_ds_bpermute(srclane << 2, __float_as_int(v)));
}

// ---------- conversion kernels ----------
__global__ void k_cvt(const float* __restrict__ src, unsigned short* __restrict__ dst, int n4) {
    int i = blockIdx.x * blockDim.x + threadIdx.x;
    if (i < n4) {
        float4 v = reinterpret_cast<const float4*>(src)[i];
        ushort4 o;
        o.x = f2bf(v.x); o.y = f2bf(v.y); o.z = f2bf(v.z); o.w = f2bf(v.w);
        reinterpret_cast<ushort4*>(dst)[i] = o;
    }
}

// Wq/Wk/Wv [H=16][C=1024][S=64] f32 -> Wt [n=sec*1024+h*64+s][c] bf16 (K-contiguous)
__global__ void k_cvt_wt(const float* __restrict__ Wq, const float* __restrict__ Wk,
                         const float* __restrict__ Wv, unsigned short* __restrict__ Wt) {
    __shared__ unsigned short lt[64][72];
    int bid = blockIdx.x;
    int ct  = bid & 15;
    int h   = (bid >> 4) & 15;
    int sec = bid >> 8;
    const float* W = (sec == 0) ? Wq : ((sec == 1) ? Wk : Wv);
    int t = threadIdx.x;
    #pragma unroll
    for (int q = 0; q < 4; q++) {
        int id = t + q * 256;
        int c  = id >> 4;
        int s4 = (id & 15) * 4;
        float4 v = *reinterpret_cast<const float4*>(&W[((size_t)(h * 1024) + (ct * 64 + c)) * 64 + s4]);
        lt[s4 + 0][c] = f2bf(v.x);
        lt[s4 + 1][c] = f2bf(v.y);
        lt[s4 + 2][c] = f2bf(v.z);
        lt[s4 + 3][c] = f2bf(v.w);
    }
    __syncthreads();
    #pragma unroll
    for (int q = 0; q < 2; q++) {
        int id = t + q * 256;
        int s  = id >> 3;
        int c8 = (id & 7) * 8;
        bf16x8 val = *reinterpret_cast<const bf16x8*>(&lt[s][c8]);
        int n = sec * 1024 + h * 64 + s;
        *reinterpret_cast<bf16x8*>(&Wt[(size_t)n * 1024 + ct * 64 + c8]) = val;
    }
}

// ---------- GEMM (m97 structure + BK=64 + XOR-swizzled LDS + XCD remap) ----------
template <int MODE>
__launch_bounds__(256)
__global__ void k_gemm(const unsigned short* __restrict__ A,
                       const unsigned short* __restrict__ Bt,
                       int M, int N, int K,
                       unsigned short* __restrict__ q_nat,
                       unsigned short* __restrict__ k_nat,
                       unsigned short* __restrict__ vT,
                       float* __restrict__ out, const float* __restrict__ bp) {
    __shared__ unsigned short Asm[128][64];   // 16 KB, rows XOR-swizzled (granule ^= row&7)
    __shared__ unsigned short Bsm[128][64];
    const int nb = N >> 7;
    int cpx = gridDim.x >> 3;
    int bid = (blockIdx.x & 7) * cpx + (blockIdx.x >> 3);   // T1 bijective XCD remap
    int n0 = (bid % nb) << 7;
    int m0 = (bid / nb) << 7;
    int t = threadIdx.x;
    int lane = t & 63, w = t >> 6;
    int wr = w >> 1, wc = w & 1;
    int l15 = lane & 15, lg = lane >> 4;
    int sr = lane >> 3;
    int scol = ((lane & 7) ^ sr) << 3;

    f32x4 acc[4][4];
    #pragma unroll
    for (int i = 0; i < 4; i++)
        #pragma unroll
        for (int j = 0; j < 4; j++) acc[i][j] = (f32x4){0.f, 0.f, 0.f, 0.f};

    for (int kt = 0; kt < K; kt += 64) {
        #pragma unroll
        for (int q = 0; q < 4; q++) {
            int rb = q * 32 + w * 8;
            int row = rb + sr;
            gload_lds16(&A[(size_t)(m0 + row) * K + kt + scol], &Asm[rb][0]);
            gload_lds16(&Bt[(size_t)(n0 + row) * K + kt + scol], &Bsm[rb][0]);
        }
        __syncthreads();
        bf16x8 af[4][2], bfr[4][2];
        int x15 = (l15 & 7) << 3;
        #pragma unroll
        for (int mi = 0; mi < 4; mi++) {
            int row = wr * 64 + mi * 16 + l15;
            af[mi][0] = *reinterpret_cast<const bf16x8*>(&Asm[row][(lg * 8) ^ x15]);
            af[mi][1] = *reinterpret_cast<const bf16x8*>(&Asm[row][(32 + lg * 8) ^ x15]);
        }
        #pragma unroll
        for (int nj = 0; nj < 4; nj++) {
            int row = wc * 64 + nj * 16 + l15;
            bfr[nj][0] = *reinterpret_cast<const bf16x8*>(&Bsm[row][(lg * 8) ^ x15]);
            bfr[nj][1] = *reinterpret_cast<const bf16x8*>(&Bsm[row][(32 + lg * 8) ^ x15]);
        }
        #pragma unroll
        for (int mi = 0; mi < 4; mi++)
            #pragma unroll
            for (int nj = 0; nj < 4; nj++) {
                acc[mi][nj] = __builtin_amdgcn_mfma_f32_16x16x32_bf16(af[mi][0], bfr[nj][0], acc[mi][nj], 0, 0, 0);
                acc[mi][nj] = __builtin_amdgcn_mfma_f32_16x16x32_bf16(af[mi][1], bfr[nj][1], acc[mi][nj], 0, 0, 0);
            }
        __syncthreads();
    }

    #pragma unroll
    for (int mi = 0; mi < 4; mi++) {
        #pragma unroll
        for (int nj = 0; nj < 4; nj++) {
            #pragma unroll
            for (int r = 0; r < 4; r++) {
                int m = m0 + wr * 64 + mi * 16 + lg * 4 + r;
                int n = n0 + wc * 64 + nj * 16 + l15;
                float v = acc[mi][nj][r];
                if (MODE == 0) {
                    int sec = n >> 10;
                    int win = n & 1023;
                    if (sec == 0) {
                        q_nat[(size_t)m * 1024 + win] = f2bf(v * 0.1803368801f);  // 1/sqrt(S)*log2e
                    } else if (sec == 1) {
                        k_nat[(size_t)m * 1024 + win] = f2bf(v);
                    } else {
                        int b = m >> 11, tt = m & 2047;
                        int h = win >> 6, s = win & 63;
                        vT[(((size_t)(b * 16 + h)) * 64 + s) * 2048 + tt] = f2bf(v);
                    }
                } else {
                    out[(size_t)m * 1024 + n] = v + bp[n];
                }
            }
        }
    }
}

// ---------- flash attention: register-direct (no LDS, no barriers) ----------
// 2048 one-wave blocks; wave owns 32 q-rows (g = row-group 0..63 per (b,h)), loops its
// kv tiles loading K/V MFMA fragments straight from global (L2-resident panels).
// Launch index d: xcd-cluster bh = (d&7)|(((d>>3)&3)<<3); g = 63-(d>>5) (longest first).
__launch_bounds__(64, 2)
__global__ void k_attn(const unsigned short* __restrict__ q_nat,
                       const unsigned short* __restrict__ k_nat,
                       const unsigned short* __restrict__ vT,
                       unsigned short* __restrict__ y_bf) {
    const int T = 2048, H = 16;
    int d = blockIdx.x;
    int bh = (d & 7) | (((d >> 3) & 3) << 3);   // 4 (b,h) panels per XCD -> 2MB in L2
    int g  = 63 - (d >> 5);                     // longest blocks dispatched first
    int h = bh & 15, b = bh >> 4;
    int lane = threadIdx.x;
    int l31 = lane & 31, hi = lane >> 5;
    int warp_q0 = g * 32;
    int qg = warp_q0 + l31;                     // this lane's q-row (S^T col)
    int ntile = (warp_q0 >> 6) + 1;             // kv tiles j = 0..ntile-1

    const unsigned short* kbase = k_nat + (size_t)(b * T) * 1024 + h * 64;
    const unsigned short* vbase = vT + ((size_t)(b * H + h) * 64) * 2048;

    // Q fragments (B operand): lane holds Q[q=qg][k = tt*16 + hi*8 + 0..7] (exp2-prescaled)
    bf16x8 qf[4];
    #pragma unroll
    for (int tt = 0; tt < 4; tt++)
        qf[tt] = *reinterpret_cast<const bf16x8*>(
            q_nat + (size_t)(b * T + qg) * 1024 + h * 64 + tt * 16 + hi * 8);

    f32x16 acc0, acc1;                   // O cols s = l31, 32+l31; rows via 32x32 C-layout
    #pragma unroll
    for (int r = 0; r < 16; r++) { acc0[r] = 0.f; acc1[r] = 0.f; }
    float m = -INFINITY, ell = 0.f;

    for (int j = 0; j < ntile; j++) {
        const unsigned short* krow = kbase + (size_t)(j * 64) * 1024;
        // K fragments: lane holds K[kv = l31 (+32)][d-slice tt*16 + hi*8] (A operand)
        bf16x8 kf0[4], kf1[4];
        #pragma unroll
        for (int tt = 0; tt < 4; tt++) {
            kf0[tt] = *reinterpret_cast<const bf16x8*>(krow + (size_t)l31 * 1024 + tt * 16 + hi * 8);
            kf1[tt] = *reinterpret_cast<const bf16x8*>(krow + (size_t)(32 + l31) * 1024 + tt * 16 + hi * 8);
        }
        // V fragments: lane holds V^T[s = l31 (+32)][kv-slice ks*16 + hi*8] (B operand)
        bf16x8 vf0[4], vf1[4];
        #pragma unroll
        for (int ks = 0; ks < 4; ks++) {
            vf0[ks] = *reinterpret_cast<const bf16x8*>(vbase + (size_t)l31 * 2048 + j * 64 + ks * 16 + hi * 8);
            vf1[ks] = *reinterpret_cast<const bf16x8*>(vbase + (size_t)(32 + l31) * 2048 + j * 64 + ks * 16 + hi * 8);
        }

        // S^T = K · Q^T
        f32x16 s0, s1;
        #pragma unroll
        for (int r = 0; r < 16; r++) { s0[r] = 0.f; s1[r] = 0.f; }
        __builtin_amdgcn_s_setprio(1);
        #pragma unroll
        for (int tt = 0; tt < 4; tt++) {
            s0 = __builtin_amdgcn_mfma_f32_32x32x16_bf16(kf0[tt], qf[tt], s0, 0, 0, 0);
            s1 = __builtin_amdgcn_mfma_f32_32x32x16_bf16(kf1[tt], qf[tt], s1, 0, 0, 0);
        }
        __builtin_amdgcn_s_setprio(0);

        // causal mask (last tile only)
        if (j == ntile - 1) {
            #pragma unroll
            for (int r = 0; r < 16; r++) {
                int kvr = (r & 3) + 8 * (r >> 2) + 4 * hi + j * 64;
                if (kvr > qg) s0[r] = -INFINITY;
                if (kvr + 32 > qg) s1[r] = -INFINITY;
            }
        }

        // row max (in-lane + lane^32 exchange)
        float tmax = -INFINITY;
        #pragma unroll
        for (int r = 0; r < 16; r++) tmax = fmaxf(tmax, fmaxf(s0[r], s1[r]));
        tmax = fmaxf(tmax, __shfl_xor(tmax, 32, 64));

        // defer-max (T13, exp2 domain THR ~ 11.5)
        if (!__all(tmax <= m + 11.5f)) {
            float mn = fmaxf(m, tmax);
            float scl = fast_exp2(m - mn);
            m = mn; ell *= scl;
            #pragma unroll
            for (int r = 0; r < 16; r++) {
                float sv = bperm_f((r & 3) + 8 * (r >> 2) + 4 * hi, scl);
                acc0[r] *= sv; acc1[r] *= sv;
            }
        }

        // P = 2^(S - m), row sum
        float rs = 0.f;
        #pragma unroll
        for (int r = 0; r < 16; r++) {
            s0[r] = fast_exp2(s0[r] - m); rs += s0[r];
            s1[r] = fast_exp2(s1[r] - m); rs += s1[r];
        }
        rs += __shfl_xor(rs, 32, 64);
        ell += rs;

        // pack P to bf16 pairs
        unsigned int c[16];
        #pragma unroll
        for (int i2 = 0; i2 < 8; i2++) {
            asm("v_cvt_pk_bf16_f32 %0, %1, %2" : "=v"(c[i2]) : "v"(s0[2 * i2]), "v"(s0[2 * i2 + 1]));
            asm("v_cvt_pk_bf16_f32 %0, %1, %2" : "=v"(c[8 + i2]) : "v"(s1[2 * i2]), "v"(s1[2 * i2 + 1]));
        }
        // assemble PV A-frags via lane^32 exchange
        bf16x8 pa[4];
        #pragma unroll
        for (int ks = 0; ks < 4; ks++) {
            unsigned int clo0 = c[ks * 4 + 0], clo1 = c[ks * 4 + 1];
            unsigned int chi0 = c[ks * 4 + 2], chi1 = c[ks * 4 + 3];
            unsigned int pl0 = (unsigned int)__shfl_xor((int)clo0, 32, 64);
            unsigned int pl1 = (unsigned int)__shfl_xor((int)clo1, 32, 64);
            unsigned int ph0 = (unsigned int)__shfl_xor((int)chi0, 32, 64);
            unsigned int ph1 = (unsigned int)__shfl_xor((int)chi1, 32, 64);
            union { unsigned int u[4]; bf16x8 v; } fr;
            fr.u[0] = hi ? ph0 : clo0;
            fr.u[1] = hi ? ph1 : clo1;
            fr.u[2] = hi ? chi0 : pl0;
            fr.u[3] = hi ? chi1 : pl1;
            pa[ks] = fr.v;
        }

        // O += P · V
        __builtin_amdgcn_s_setprio(1);
        #pragma unroll
        for (int ks = 0; ks < 4; ks++) {
            acc0 = __builtin_amdgcn_mfma_f32_32x32x16_bf16(pa[ks], vf0[ks], acc0, 0, 0, 0);
            acc1 = __builtin_amdgcn_mfma_f32_32x32x16_bf16(pa[ks], vf1[ks], acc1, 0, 0, 0);
        }
        __builtin_amdgcn_s_setprio(0);
    }

    // epilogue: O / ell
    float rinv = 1.0f / ell;
    #pragma unroll
    for (int r = 0; r < 16; r++) {
        int qr = (r & 3) + 8 * (r >> 2) + 4 * hi;
        float rv = bperm_f(qr, rinv);
        size_t row = (size_t)(b * T + warp_q0 + qr) * 1024 + h * 64;
        y_bf[row + l31] = f2bf(acc0[r] * rv);
        y_bf[row + 32 + l31] = f2bf(acc1[r] * rv);
    }
}

// ---------- launch ----------
extern "C" void kernel_launch(void* const* d_in, const int* in_sizes, int n_in,
                              void* d_out, int out_size, void* d_ws, size_t ws_size,
                              hipStream_t stream) {
    const float* x  = (const float*)d_in[0];
    const float* Wq = (const float*)d_in[1];
    const float* Wk = (const float*)d_in[2];
    const float* Wv = (const float*)d_in[3];
    const float* Wp = (const float*)d_in[4];
    const float* bp = (const float*)d_in[5];
    float* out = (float*)d_out;

    char* ws = (char*)d_ws;
    unsigned short* x_bf  = (unsigned short*)(ws);                           // 8 MB
    unsigned short* Wt    = (unsigned short*)(ws + ((size_t)8  << 20));      // 6 MB
    unsigned short* Wp_bf = (unsigned short*)(ws + ((size_t)14 << 20));      // 2 MB
    unsigned short* q_nat = (unsigned short*)(ws + ((size_t)16 << 20));      // 8 MB
    unsigned short* k_nat = (unsigned short*)(ws + ((size_t)24 << 20));      // 8 MB
    unsigned short* vT    = (unsigned short*)(ws + ((size_t)32 << 20));      // 8 MB
    unsigned short* y_bf  = (unsigned short*)(ws + ((size_t)40 << 20));      // 8 MB

    k_cvt<<<4096, 256, 0, stream>>>(x, x_bf, 4194304 / 4);
    k_cvt<<<1024, 256, 0, stream>>>(Wp, Wp_bf, 1048576 / 4);
    k_cvt_wt<<<768, 256, 0, stream>>>(Wq, Wk, Wv, Wt);
    k_gemm<0><<<24 * 32, 256, 0, stream>>>(x_bf, Wt, 4096, 3072, 1024,
                                           q_nat, k_nat, vT, nullptr, nullptr);
    k_attn<<<2048, 64, 0, stream>>>(q_nat, k_nat, vT, y_bf);
    k_gemm<1><<<8 * 32, 256, 0, stream>>>(y_bf, Wp_bf, 4096, 1024, 1024,
                                          nullptr, nullptr, nullptr, out, bp);
}

// Round 9
// 118.165 us; speedup vs baseline: 1.2616x; 1.2616x over previous
//
#include <hip/hip_runtime.h>
#include <hip/hip_bf16.h>
#include <cmath>

// ---------- types ----------
typedef __attribute__((ext_vector_type(8))) short bf16x8;    // 8 bf16 (4 VGPRs) MFMA A/B frag
typedef __attribute__((ext_vector_type(4))) float f32x4;     // 16x16 C/D frag
typedef __attribute__((ext_vector_type(16))) float f32x16;   // 32x32 C/D frag

__device__ __forceinline__ unsigned short f2bf(float f) {
    union { float f; unsigned int i; } c; c.f = f;
    unsigned int i = c.i;
    unsigned int r = i + 0x7FFF + ((i >> 16) & 1);   // RTNE
    return (unsigned short)(r >> 16);
}

__device__ __forceinline__ float fast_exp2(float x) {   // D = 2^x (v_exp_f32)
    float r;
    asm("v_exp_f32 %0, %1" : "=v"(r) : "v"(x));
    return r;
}

// async global->LDS, 16B/lane. LDS dest: wave-uniform base (+lane*16 implicit); global src per-lane.
__device__ __forceinline__ void gload_lds16(const unsigned short* g, unsigned short* l) {
    __builtin_amdgcn_global_load_lds((const __attribute__((address_space(1))) unsigned int*)g,
                                     (__attribute__((address_space(3))) unsigned int*)l, 16, 0, 0);
}

__device__ __forceinline__ float bperm_f(int srclane, float v) {
    return __int_as_float(__builtin_amdgcn_ds_bpermute(srclane << 2, __float_as_int(v)));
}

// ---------- conversion kernels ----------
__global__ void k_cvt(const float* __restrict__ src, unsigned short* __restrict__ dst, int n4) {
    int i = blockIdx.x * blockDim.x + threadIdx.x;
    if (i < n4) {
        float4 v = reinterpret_cast<const float4*>(src)[i];
        ushort4 o;
        o.x = f2bf(v.x); o.y = f2bf(v.y); o.z = f2bf(v.z); o.w = f2bf(v.w);
        reinterpret_cast<ushort4*>(dst)[i] = o;
    }
}

// Wq/Wk/Wv [H=16][C=1024][S=64] f32 -> Wt [n=sec*1024+h*64+s][c] bf16 (K-contiguous)
__global__ void k_cvt_wt(const float* __restrict__ Wq, const float* __restrict__ Wk,
                         const float* __restrict__ Wv, unsigned short* __restrict__ Wt) {
    __shared__ unsigned short lt[64][72];
    int bid = blockIdx.x;
    int ct  = bid & 15;
    int h   = (bid >> 4) & 15;
    int sec = bid >> 8;
    const float* W = (sec == 0) ? Wq : ((sec == 1) ? Wk : Wv);
    int t = threadIdx.x;
    #pragma unroll
    for (int q = 0; q < 4; q++) {
        int id = t + q * 256;
        int c  = id >> 4;
        int s4 = (id & 15) * 4;
        float4 v = *reinterpret_cast<const float4*>(&W[((size_t)(h * 1024) + (ct * 64 + c)) * 64 + s4]);
        lt[s4 + 0][c] = f2bf(v.x);
        lt[s4 + 1][c] = f2bf(v.y);
        lt[s4 + 2][c] = f2bf(v.z);
        lt[s4 + 3][c] = f2bf(v.w);
    }
    __syncthreads();
    #pragma unroll
    for (int q = 0; q < 2; q++) {
        int id = t + q * 256;
        int s  = id >> 3;
        int c8 = (id & 7) * 8;
        bf16x8 val = *reinterpret_cast<const bf16x8*>(&lt[s][c8]);
        int n = sec * 1024 + h * 64 + s;
        *reinterpret_cast<bf16x8*>(&Wt[(size_t)n * 1024 + ct * 64 + c8]) = val;
    }
}

// ---------- GEMM (m97 structure + BK=64 + XOR-swizzled LDS + XCD remap) ----------
template <int MODE>
__launch_bounds__(256)
__global__ void k_gemm(const unsigned short* __restrict__ A,
                       const unsigned short* __restrict__ Bt,
                       int M, int N, int K,
                       unsigned short* __restrict__ q_nat,
                       unsigned short* __restrict__ k_nat,
                       unsigned short* __restrict__ vT,
                       float* __restrict__ out, const float* __restrict__ bp) {
    __shared__ unsigned short Asm[128][64];   // 16 KB, rows XOR-swizzled (granule ^= row&7)
    __shared__ unsigned short Bsm[128][64];
    const int nb = N >> 7;
    int cpx = gridDim.x >> 3;
    int bid = (blockIdx.x & 7) * cpx + (blockIdx.x >> 3);   // T1 bijective XCD remap
    int n0 = (bid % nb) << 7;
    int m0 = (bid / nb) << 7;
    int t = threadIdx.x;
    int lane = t & 63, w = t >> 6;
    int wr = w >> 1, wc = w & 1;
    int l15 = lane & 15, lg = lane >> 4;
    int sr = lane >> 3;
    int scol = ((lane & 7) ^ sr) << 3;

    f32x4 acc[4][4];
    #pragma unroll
    for (int i = 0; i < 4; i++)
        #pragma unroll
        for (int j = 0; j < 4; j++) acc[i][j] = (f32x4){0.f, 0.f, 0.f, 0.f};

    for (int kt = 0; kt < K; kt += 64) {
        #pragma unroll
        for (int q = 0; q < 4; q++) {
            int rb = q * 32 + w * 8;
            int row = rb + sr;
            gload_lds16(&A[(size_t)(m0 + row) * K + kt + scol], &Asm[rb][0]);
            gload_lds16(&Bt[(size_t)(n0 + row) * K + kt + scol], &Bsm[rb][0]);
        }
        __syncthreads();
        bf16x8 af[4][2], bfr[4][2];
        int x15 = (l15 & 7) << 3;
        #pragma unroll
        for (int mi = 0; mi < 4; mi++) {
            int row = wr * 64 + mi * 16 + l15;
            af[mi][0] = *reinterpret_cast<const bf16x8*>(&Asm[row][(lg * 8) ^ x15]);
            af[mi][1] = *reinterpret_cast<const bf16x8*>(&Asm[row][(32 + lg * 8) ^ x15]);
        }
        #pragma unroll
        for (int nj = 0; nj < 4; nj++) {
            int row = wc * 64 + nj * 16 + l15;
            bfr[nj][0] = *reinterpret_cast<const bf16x8*>(&Bsm[row][(lg * 8) ^ x15]);
            bfr[nj][1] = *reinterpret_cast<const bf16x8*>(&Bsm[row][(32 + lg * 8) ^ x15]);
        }
        #pragma unroll
        for (int mi = 0; mi < 4; mi++)
            #pragma unroll
            for (int nj = 0; nj < 4; nj++) {
                acc[mi][nj] = __builtin_amdgcn_mfma_f32_16x16x32_bf16(af[mi][0], bfr[nj][0], acc[mi][nj], 0, 0, 0);
                acc[mi][nj] = __builtin_amdgcn_mfma_f32_16x16x32_bf16(af[mi][1], bfr[nj][1], acc[mi][nj], 0, 0, 0);
            }
        __syncthreads();
    }

    #pragma unroll
    for (int mi = 0; mi < 4; mi++) {
        #pragma unroll
        for (int nj = 0; nj < 4; nj++) {
            #pragma unroll
            for (int r = 0; r < 4; r++) {
                int m = m0 + wr * 64 + mi * 16 + lg * 4 + r;
                int n = n0 + wc * 64 + nj * 16 + l15;
                float v = acc[mi][nj][r];
                if (MODE == 0) {
                    int sec = n >> 10;
                    int win = n & 1023;
                    if (sec == 0) {
                        q_nat[(size_t)m * 1024 + win] = f2bf(v * 0.1803368801f);  // 1/sqrt(S)*log2e
                    } else if (sec == 1) {
                        k_nat[(size_t)m * 1024 + win] = f2bf(v);
                    } else {
                        int b = m >> 11, tt = m & 2047;
                        int h = win >> 6, s = win & 63;
                        vT[(((size_t)(b * 16 + h)) * 64 + s) * 2048 + tt] = f2bf(v);
                    }
                } else {
                    out[(size_t)m * 1024 + n] = v + bp[n];
                }
            }
        }
    }
}

// ---------- flash attention: 4 warps, in-block KV split, SINGLE-buffered (4 blocks/CU) ----------
// grid = 1024 blocks (b,h,qtile) longest-first; QT=64; warp (pr,rg): stream pr, q-rows rg*32..+31.
// Single K/V buffer per stream (~33 KB LDS total) -> 4 blocks/CU; cross-block TLP hides the
// per-iteration staging latency. Inner math identical to R5-verified body.
__launch_bounds__(256, 4)
__global__ void k_attn(const unsigned short* __restrict__ q_nat,
                       const unsigned short* __restrict__ k_nat,
                       const unsigned short* __restrict__ vT,
                       unsigned short* __restrict__ y_bf) {
    __shared__ __align__(16) unsigned short Ks[2][64][64];   // [stream][kv][d], rows XOR-swizzled
    __shared__ __align__(16) unsigned short Vs[2][64][64];   // [stream][d][kv], rows XOR-swizzled
    __shared__ float cm[2][64], cl[2][64];                   // per-stream row stats
    const int T = 2048, H = 16;
    int bid = blockIdx.x;
    int bh = bid & 31;
    int qi = 31 - (bid >> 5);            // kv tiles j=0..qi; longest blocks first
    int h = bh & 15, b = bh >> 4;
    int t = threadIdx.x;
    int lane = t & 63, w = t >> 6;       // 4 warps
    int pr = w >> 1, rg = w & 1;         // pr = stream, rg = row-group
    int l31 = lane & 31, hi = lane >> 5;
    int warp_q0 = qi * 64 + rg * 32;
    int qg = warp_q0 + l31;              // this lane's q-row

    int n0 = (qi >> 1) + 1;              // even-stream tile count (max)
    int nS = pr ? ((qi + 1) >> 1) : n0;  // my stream's tile count

    const unsigned short* kbase = k_nat + (size_t)(b * T) * 1024 + h * 64;
    const unsigned short* vbase = vT + ((size_t)(b * H + h) * 64) * 2048;

    // stage: my pair stages my stream's tile; per wave 8 rows/issue, 4 issues per array.
    int sxor = ((lane & 7) ^ (lane >> 3)) << 3;   // pre-swizzled source col (elems)

    auto STAGE = [&](int j) {
        #pragma unroll
        for (int r = 0; r < 4; r++) {
            int rb = r * 16 + rg * 8;             // wave-uniform row base
            int grow = rb + (lane >> 3);
            gload_lds16(kbase + (size_t)(j * 64 + grow) * 1024 + sxor, &Ks[pr][rb][0]);
            gload_lds16(vbase + (size_t)grow * 2048 + j * 64 + sxor, &Vs[pr][rb][0]);
        }
    };

    // Q fragments (B operand): lane holds Q[q=qg][k = tt*16 + hi*8 + 0..7] (exp2-prescaled)
    bf16x8 qf[4];
    #pragma unroll
    for (int tt = 0; tt < 4; tt++)
        qf[tt] = *reinterpret_cast<const bf16x8*>(
            q_nat + (size_t)(b * T + qg) * 1024 + h * 64 + tt * 16 + hi * 8);

    f32x16 acc0, acc1;                   // O cols s = l31, 32+l31; rows via 32x32 C-layout
    #pragma unroll
    for (int r = 0; r < 16; r++) { acc0[r] = 0.f; acc1[r] = 0.f; }
    float m = -INFINITY, ell = 0.f;

    for (int i = 0; i < n0; i++) {
        bool act = (i < nS);
        int j = pr + 2 * i;
        if (act) STAGE(j);               // stage this iteration's tile
        __syncthreads();                 // staging visible (compiler drains vmcnt)

        if (act) {
            const char* kb = (const char*)&Ks[pr][0][0];
            const char* vb = (const char*)&Vs[pr][0][0];
            int rsw = (l31 & 7) << 4;                     // read-side XOR

            // S^T = K · Q^T : lane holds col q=qg, rows kv per 32x32 C-layout
            f32x16 s0, s1;
            #pragma unroll
            for (int r = 0; r < 16; r++) { s0[r] = 0.f; s1[r] = 0.f; }
            __builtin_amdgcn_s_setprio(1);
            #pragma unroll
            for (int tt = 0; tt < 4; tt++) {
                int cb = (tt * 32 + hi * 16) ^ rsw;
                bf16x8 kf0 = *reinterpret_cast<const bf16x8*>(kb + l31 * 128 + cb);
                bf16x8 kf1 = *reinterpret_cast<const bf16x8*>(kb + (32 + l31) * 128 + cb);
                s0 = __builtin_amdgcn_mfma_f32_32x32x16_bf16(kf0, qf[tt], s0, 0, 0, 0);
                s1 = __builtin_amdgcn_mfma_f32_32x32x16_bf16(kf1, qf[tt], s1, 0, 0, 0);
            }
            __builtin_amdgcn_s_setprio(0);

            // causal mask (only the diagonal tile j == qi)
            if (j == qi) {
                #pragma unroll
                for (int r = 0; r < 16; r++) {
                    int kvr = (r & 3) + 8 * (r >> 2) + 4 * hi + j * 64;
                    if (kvr > qg) s0[r] = -INFINITY;
                    if (kvr + 32 > qg) s1[r] = -INFINITY;
                }
            }

            // row max (in-lane + lane^32 exchange)
            float tmax = -INFINITY;
            #pragma unroll
            for (int r = 0; r < 16; r++) tmax = fmaxf(tmax, fmaxf(s0[r], s1[r]));
            tmax = fmaxf(tmax, __shfl_xor(tmax, 32, 64));

            // defer-max (T13, exp2 domain THR ~ 11.5)
            if (!__all(tmax <= m + 11.5f)) {
                float mn = fmaxf(m, tmax);
                float scl = fast_exp2(m - mn);
                m = mn; ell *= scl;
                #pragma unroll
                for (int r = 0; r < 16; r++) {
                    float sv = bperm_f((r & 3) + 8 * (r >> 2) + 4 * hi, scl);
                    acc0[r] *= sv; acc1[r] *= sv;
                }
            }

            // P = 2^(S - m), row sum
            float rs = 0.f;
            #pragma unroll
            for (int r = 0; r < 16; r++) {
                s0[r] = fast_exp2(s0[r] - m); rs += s0[r];
                s1[r] = fast_exp2(s1[r] - m); rs += s1[r];
            }
            rs += __shfl_xor(rs, 32, 64);
            ell += rs;

            // pack P to bf16 pairs
            unsigned int c[16];
            #pragma unroll
            for (int i2 = 0; i2 < 8; i2++) {
                asm("v_cvt_pk_bf16_f32 %0, %1, %2" : "=v"(c[i2]) : "v"(s0[2 * i2]), "v"(s0[2 * i2 + 1]));
                asm("v_cvt_pk_bf16_f32 %0, %1, %2" : "=v"(c[8 + i2]) : "v"(s1[2 * i2]), "v"(s1[2 * i2 + 1]));
            }
            // assemble PV A-frags via lane^32 exchange
            bf16x8 pa[4];
            #pragma unroll
            for (int ks = 0; ks < 4; ks++) {
                unsigned int clo0 = c[ks * 4 + 0], clo1 = c[ks * 4 + 1];
                unsigned int chi0 = c[ks * 4 + 2], chi1 = c[ks * 4 + 3];
                unsigned int pl0 = (unsigned int)__shfl_xor((int)clo0, 32, 64);
                unsigned int pl1 = (unsigned int)__shfl_xor((int)clo1, 32, 64);
                unsigned int ph0 = (unsigned int)__shfl_xor((int)chi0, 32, 64);
                unsigned int ph1 = (unsigned int)__shfl_xor((int)chi1, 32, 64);
                union { unsigned int u[4]; bf16x8 v; } fr;
                fr.u[0] = hi ? ph0 : clo0;
                fr.u[1] = hi ? ph1 : clo1;
                fr.u[2] = hi ? chi0 : pl0;
                fr.u[3] = hi ? chi1 : pl1;
                pa[ks] = fr.v;
            }

            // O += P · V
            __builtin_amdgcn_s_setprio(1);
            #pragma unroll
            for (int ks = 0; ks < 4; ks++) {
                int cb = (ks * 32 + hi * 16) ^ rsw;
                bf16x8 v0 = *reinterpret_cast<const bf16x8*>(vb + l31 * 128 + cb);
                bf16x8 v1 = *reinterpret_cast<const bf16x8*>(vb + (32 + l31) * 128 + cb);
                acc0 = __builtin_amdgcn_mfma_f32_32x32x16_bf16(pa[ks], v0, acc0, 0, 0, 0);
                acc1 = __builtin_amdgcn_mfma_f32_32x32x16_bf16(pa[ks], v1, acc1, 0, 0, 0);
            }
            __builtin_amdgcn_s_setprio(0);
        }

        __syncthreads();             // all warps done reading before next stage overwrites
    }

    // ---- cross-stream merge: (m0,l0,O0) + (m1,l1,O1) ----
    if (hi == 0) { cm[pr][rg * 32 + l31] = m; cl[pr][rg * 32 + l31] = ell; }
    __syncthreads();

    int rowi = rg * 32 + l31;
    float m0v = cm[0][rowi], l0v = cl[0][rowi];
    float m1v = cm[1][rowi], l1v = cl[1][rowi];
    float mSt = fmaxf(m0v, m1v);
    float w0 = (m0v > -1e30f) ? fast_exp2(m0v - mSt) : 0.f;
    float w1 = (m1v > -1e30f) ? fast_exp2(m1v - mSt) : 0.f;
    float denom = 1.f / (l0v * w0 + l1v * w1);
    float myw = pr ? w1 : w0;

    float* Ocomb = (float*)&Ks[0][0][0];      // 64 x 64 f32 = 16 KB (reuse staging LDS)
    if (pr == 1) {
        #pragma unroll
        for (int r = 0; r < 16; r++) {
            int qr = (r & 3) + 8 * (r >> 2) + 4 * hi;
            float sB = bperm_f(qr, myw);
            Ocomb[(rg * 32 + qr) * 64 + l31] = acc0[r] * sB;
            Ocomb[(rg * 32 + qr) * 64 + 32 + l31] = acc1[r] * sB;
        }
    }
    __syncthreads();
    if (pr == 0) {
        #pragma unroll
        for (int r = 0; r < 16; r++) {
            int qr = (r & 3) + 8 * (r >> 2) + 4 * hi;
            float sA = bperm_f(qr, myw);
            float dv = bperm_f(qr, denom);
            float o0 = acc0[r] * sA + Ocomb[(rg * 32 + qr) * 64 + l31];
            float o1 = acc1[r] * sA + Ocomb[(rg * 32 + qr) * 64 + 32 + l31];
            size_t row = (size_t)(b * T + warp_q0 + qr) * 1024 + h * 64;
            y_bf[row + l31] = f2bf(o0 * dv);
            y_bf[row + 32 + l31] = f2bf(o1 * dv);
        }
    }
}

// ---------- launch ----------
extern "C" void kernel_launch(void* const* d_in, const int* in_sizes, int n_in,
                              void* d_out, int out_size, void* d_ws, size_t ws_size,
                              hipStream_t stream) {
    const float* x  = (const float*)d_in[0];
    const float* Wq = (const float*)d_in[1];
    const float* Wk = (const float*)d_in[2];
    const float* Wv = (const float*)d_in[3];
    const float* Wp = (const float*)d_in[4];
    const float* bp = (const float*)d_in[5];
    float* out = (float*)d_out;

    char* ws = (char*)d_ws;
    unsigned short* x_bf  = (unsigned short*)(ws);                           // 8 MB
    unsigned short* Wt    = (unsigned short*)(ws + ((size_t)8  << 20));      // 6 MB
    unsigned short* Wp_bf = (unsigned short*)(ws + ((size_t)14 << 20));      // 2 MB
    unsigned short* q_nat = (unsigned short*)(ws + ((size_t)16 << 20));      // 8 MB
    unsigned short* k_nat = (unsigned short*)(ws + ((size_t)24 << 20));      // 8 MB
    unsigned short* vT    = (unsigned short*)(ws + ((size_t)32 << 20));      // 8 MB
    unsigned short* y_bf  = (unsigned short*)(ws + ((size_t)40 << 20));      // 8 MB

    k_cvt<<<4096, 256, 0, stream>>>(x, x_bf, 4194304 / 4);
    k_cvt<<<1024, 256, 0, stream>>>(Wp, Wp_bf, 1048576 / 4);
    k_cvt_wt<<<768, 256, 0, stream>>>(Wq, Wk, Wv, Wt);
    k_gemm<0><<<24 * 32, 256, 0, stream>>>(x_bf, Wt, 4096, 3072, 1024,
                                           q_nat, k_nat, vT, nullptr, nullptr);
    k_attn<<<1024, 256, 0, stream>>>(q_nat, k_nat, vT, y_bf);
    k_gemm<1><<<8 * 32, 256, 0, stream>>>(y_bf, Wp_bf, 4096, 1024, 1024,
                                          nullptr, nullptr, nullptr, out, bp);
}